// Round 11
// baseline (143.724 us; speedup 1.0000x reference)
//
#include <hip/hip_runtime.h>
#include <math.h>

#define NUM_I 100
#define NZ    16
#define NCAND (NUM_I * NZ)     // 1600
#define NBL   4096             // local LDS bins (value-linear over global [min,max])
#define G2    256              // main grid: 1 block/CU -> all co-resident (gbar-safe)
#define BLK   1024             // 16 waves/block -> 16 waves/CU
#define SLICE 16384            // elements per block
#define BPT   (NBL / BLK)      // 4 bins per thread
#define F32_EPS 1.1920928955078125e-07f
#define AGENT __HIP_MEMORY_SCOPE_AGENT

// ---------------- workspace layout ----------------
struct WSL {
    unsigned* ctrs;            // 16 slots ([0]=gbar, [1]=final ticket) -- memset 64 B
    double*   score;           // 1600 cells (zeroed in-kernel pre-gbar0; shifted by -sum(x^2))
    float*    pmin; float* pmax;           // G2 partials
    float4*   params; float2* ranges; float* mm;   // fallback path only
    double*   scoreFB;
    size_t    small_needed;
};

__host__ __device__ static inline WSL make_ws(char* w0) {
    WSL L; char* w = w0;
    L.ctrs   = (unsigned*)w; w += 64;
    L.score  = (double*)w;   w += sizeof(double) * NCAND;
    L.pmin   = (float*)w;    w += sizeof(float) * G2;
    L.pmax   = (float*)w;    w += sizeof(float) * G2;
    L.params = (float4*)w;   w += sizeof(float4) * NCAND;
    L.ranges = (float2*)w;   w += sizeof(float2) * NCAND;
    L.mm     = (float*)w;    w += sizeof(float) * 4;
    size_t head = (size_t)(w - w0);
    L.small_needed = (head + 15) & ~(size_t)15;
    L.scoreFB = L.score;
    return L;
}

// ---------------- device helpers ----------------
static __device__ __forceinline__ float rfl_f(float v) {
    return __int_as_float(__builtin_amdgcn_readfirstlane(__float_as_int(v)));
}
static __device__ __forceinline__ double agent_load_f64(const double* p) {
    return __hip_atomic_load(p, __ATOMIC_RELAXED, AGENT);
}
// monotone value->local-bin map, shared by elements and thresholds (exactness
// needs only monotonicity: bin(v)<bin(t) => v<t ; bin(v)>bin(t) => v>=t).
static __device__ __forceinline__ int bin_loc(float v, float lo, float invw) {
    int b = (int)floorf((v - lo) * invw);
    return min(max(b, 0), NBL - 1);
}
// round-6/8-proven global barrier (tid0-only cache maintenance; all blocks co-resident)
static __device__ __forceinline__ void gbar(unsigned* ctr, int nblk) {
    __syncthreads();
    if (threadIdx.x == 0) {
        __hip_atomic_fetch_add(ctr, 1u, __ATOMIC_ACQ_REL, AGENT);
        while (__hip_atomic_load(ctr, __ATOMIC_RELAXED, AGENT) < (unsigned)nblk)
            __builtin_amdgcn_s_sleep(8);
        (void)__hip_atomic_load(ctr, __ATOMIC_ACQUIRE, AGENT);
    }
    __syncthreads();
}

// ============ the fused kernel: minmax -> gbar -> local sort+moments -> scores -> argmin ============
__global__ __launch_bounds__(BLK, 4) void k_fused(const float* __restrict__ x, int n4,
                                                  char* wsbase, float* __restrict__ out) {
    WSL L = make_ws(wsbase);
    __shared__ __align__(16) float ssort[SLICE];   // 64 KB
    __shared__ unsigned Cb[NBL];                   // 16 KB (counts -> starts -> ends)
    __shared__ double   S1p[NBL];                  // 32 KB (bin sum(x) -> excl prefix)
    __shared__ double   dpart[BLK];                //  8 KB scratch (f64 scan / argmin / f32 minmax)
    __shared__ unsigned upart[BLK];                //  4 KB scratch (u32 scan / argmin idx)
    __shared__ double   stot[1];
    __shared__ float    sxm[2];
    __shared__ int      islast;
    const int tid = threadIdx.x, blk = blockIdx.x;
    const float4* x4 = (const float4*)x;
    const int per4 = (n4 + G2 - 1) / G2;
    const int beg4 = blk * per4, end4 = min(beg4 + per4, n4);
    const int len = (end4 > beg4) ? (end4 - beg4) * 4 : 0;

    // ---- Ph A: zero score slice + block min/max partial over own slice ----
    {
        int gtid = blk * BLK + tid;
        if (gtid < NCAND) L.score[gtid] = 0.0;     // published by gbar0
        float* rmin = (float*)dpart; float* rmax = rmin + BLK;   // 8 KB = dpart
        float lmin = 3.0e38f, lmax = -3.0e38f;
        for (int i = beg4 + tid; i < end4; i += BLK) {
            float4 v = x4[i];
            lmin = fminf(lmin, fminf(fminf(v.x, v.y), fminf(v.z, v.w)));
            lmax = fmaxf(lmax, fmaxf(fmaxf(v.x, v.y), fmaxf(v.z, v.w)));
        }
        rmin[tid] = lmin; rmax[tid] = lmax;
        __syncthreads();
        for (int s = BLK / 2; s > 0; s >>= 1) {
            if (tid < s) {
                rmin[tid] = fminf(rmin[tid], rmin[tid + s]);
                rmax[tid] = fmaxf(rmax[tid], rmax[tid + s]);
            }
            __syncthreads();
        }
        if (tid == 0) { L.pmin[blk] = rmin[0]; L.pmax[blk] = rmax[0]; }
    }
    gbar(&L.ctrs[0], G2);    // publishes pmin/pmax + zeroed score

    // ---- Ph B: every block redundantly reduces partials (identical order => identical result) ----
    {
        float* rmin = (float*)dpart; float* rmax = rmin + BLK;
        float lmin = (tid < G2) ? L.pmin[tid] : 3.0e38f;
        float lmax = (tid < G2) ? L.pmax[tid] : -3.0e38f;
        rmin[tid] = lmin; rmax[tid] = lmax;
        __syncthreads();
        for (int s = BLK / 2; s > 0; s >>= 1) {
            if (tid < s) {
                rmin[tid] = fminf(rmin[tid], rmin[tid + s]);
                rmax[tid] = fmaxf(rmax[tid], rmax[tid + s]);
            }
            __syncthreads();
        }
        if (tid == 0) { sxm[0] = rmin[0]; sxm[1] = rmax[0]; }
        __syncthreads();
    }
    const float x_min = sxm[0], x_max = sxm[1];
    const float rangef = x_max - x_min;
    const float lo = x_min;
    const float invw = (rangef > 0.0f) ? ((float)NBL / rangef) : 0.0f;

    if (len > 0) {
        // ---- Ph C: local histogram ----
        for (int b = tid; b < NBL; b += BLK) Cb[b] = 0u;
        __syncthreads();
        for (int i = beg4 + tid; i < end4; i += BLK) {
            float4 v = x4[i];
            atomicAdd(&Cb[bin_loc(v.x, lo, invw)], 1u);
            atomicAdd(&Cb[bin_loc(v.y, lo, invw)], 1u);
            atomicAdd(&Cb[bin_loc(v.z, lo, invw)], 1u);
            atomicAdd(&Cb[bin_loc(v.w, lo, invw)], 1u);
        }
        __syncthreads();
        // ---- Ph D: exclusive prefix of counts ----
        unsigned cl[BPT]; unsigned ps = 0;
        #pragma unroll
        for (int k = 0; k < BPT; k++) { cl[k] = Cb[tid * BPT + k]; ps += cl[k]; }
        upart[tid] = ps;
        __syncthreads();
        for (int off = 1; off < BLK; off <<= 1) {
            unsigned v = (tid >= off) ? upart[tid - off] : 0u;
            __syncthreads();
            upart[tid] += v;
            __syncthreads();
        }
        unsigned run = upart[tid] - ps;
        #pragma unroll
        for (int k = 0; k < BPT; k++) { Cb[tid * BPT + k] = run; run += cl[k]; }
        __syncthreads();
        // ---- Ph E: scatter into LDS (Cb mutates starts -> ends) ----
        for (int i = beg4 + tid; i < end4; i += BLK) {
            float4 v = x4[i];
            unsigned p;
            p = atomicAdd(&Cb[bin_loc(v.x, lo, invw)], 1u); ssort[p] = v.x;
            p = atomicAdd(&Cb[bin_loc(v.y, lo, invw)], 1u); ssort[p] = v.y;
            p = atomicAdd(&Cb[bin_loc(v.z, lo, invw)], 1u); ssort[p] = v.z;
            p = atomicAdd(&Cb[bin_loc(v.w, lo, invw)], 1u); ssort[p] = v.w;
        }
        __syncthreads();
        // ---- Ph F1: per-bin sum(x), STRIDED bin assignment (wave load balance) ----
        for (int k = 0; k < BPT; k++) {
            int b = tid + k * BLK;
            unsigned st = (b == 0) ? 0u : Cb[b - 1], en = Cb[b];
            double s1 = 0.0;
            for (unsigned i = st; i < en; i++) s1 += (double)ssort[i];
            S1p[b] = s1;                   // temporarily per-bin sums
        }
        __syncthreads();
        // ---- Ph F2: exclusive prefix of sums (contiguous BPT bins/thread) ----
        double l1[BPT];
        double a1 = 0.0;
        #pragma unroll
        for (int k = 0; k < BPT; k++) { l1[k] = S1p[tid * BPT + k]; a1 += l1[k]; }
        dpart[tid] = a1;
        __syncthreads();
        for (int off = 1; off < BLK; off <<= 1) {
            double v1 = (tid >= off) ? dpart[tid - off] : 0.0;
            __syncthreads();
            dpart[tid] += v1;
            __syncthreads();
        }
        double b1 = dpart[tid] - a1;
        #pragma unroll
        for (int k = 0; k < BPT; k++) {
            int b = tid * BPT + k;
            S1p[b] = b1; b1 += l1[k];
        }
        if (tid == BLK - 1) stot[0] = dpart[BLK - 1];
        __syncthreads();

        // ---- Ph G: Abel-form per-boundary terms; 16 lanes per candidate ----
        // score = ms15^2*len - 2*ms15*totS1 - sum_{j=0..14}[ s^2(2(j-zi)+1)*C_j - 2s*S1_j ]
        // (summation by parts of the telescoped form; boundary terms independent)
        {
            const double totS1 = stot[0];
            const int group = tid >> 4;        // 64 candidate-groups per block
            const int l     = tid & 15;        // lane role: boundary l (l<15) or global term (l==15)
            for (int q = 0; q < NCAND / 64; q++) {          // 25 passes x 64 cands
                int cand = (q * 64 + group + blk) % NCAND;  // bijection per block, staggered
                int zi; double sd;
                {
#pragma clang fp contract(off)
                    float step = rangef / 100.0f;
                    int ii = cand >> 4, z = cand & 15;
                    float fi = (float)(ii + 1);
                    float tmp_max   = step * fi;
                    float tmp_delta = tmp_max / 15.0f;
                    float t = (float)z * tmp_delta;
                    float new_min = fmaxf(-t, x_min);
                    float new_max = fminf(tmp_max - t, x_max);
                    float min_neg = fminf(new_min, 0.0f);
                    float max_pos = fmaxf(new_max, 0.0f);
                    float scale = fmaxf((max_pos - min_neg) / 15.0f, F32_EPS);
                    float zp = 0.0f - rintf(min_neg / scale);
                    zp = fminf(fmaxf(zp, 0.0f), 15.0f);
                    zi = (int)zp; sd = (double)scale;
                }
                double term;
                if (l < 15) {
                    double td = ((double)(l - zi) + 0.5) * sd;
                    float tf = (float)td;
                    int bf = bin_loc(tf, lo, invw);
                    unsigned st = (bf == 0) ? 0u : Cb[bf - 1], en = Cb[bf];
                    unsigned cnt = 0; double s1 = 0.0;
                    unsigned i = st;
                    for (; i < en && (i & 3u); i++) {               // align head
                        float v = ssort[i];
                        if (v < tf) { cnt++; s1 += (double)v; }
                    }
                    for (; i + 4u <= en; i += 4u) {                 // ds_read_b128 body
                        float4 v4 = *reinterpret_cast<const float4*>(&ssort[i]);
                        float m0 = (v4.x < tf) ? v4.x : 0.0f;
                        float m1 = (v4.y < tf) ? v4.y : 0.0f;
                        float m2 = (v4.z < tf) ? v4.z : 0.0f;
                        float m3 = (v4.w < tf) ? v4.w : 0.0f;
                        cnt += (v4.x < tf); cnt += (v4.y < tf);
                        cnt += (v4.z < tf); cnt += (v4.w < tf);
                        s1 += (double)((m0 + m1) + (m2 + m3));
                    }
                    for (; i < en; i++) {                           // tail
                        float v = ssort[i];
                        if (v < tf) { cnt++; s1 += (double)v; }
                    }
                    double Cj = (double)st + (double)cnt;
                    double Sj = S1p[bf] + s1;
                    term = 2.0 * sd * Sj - sd * sd * (double)(2 * (l - zi) + 1) * Cj;
                } else {
                    double ms15 = (double)(15 - zi) * sd;
                    term = ms15 * ((double)len * ms15 - 2.0 * totS1);
                }
                // reduce the 16-lane group (xor masks stay within aligned 16-lane blocks)
                term += __shfl_xor(term, 1);
                term += __shfl_xor(term, 2);
                term += __shfl_xor(term, 4);
                term += __shfl_xor(term, 8);
                if (l == 0) atomicAdd(&L.score[cand], term);   // device-scope fp64
            }
        }
    }

    // ---- Ph H: last-block ticket + argmin (round-7-proven pattern) ----
    __syncthreads();
    if (tid == 0) {
        __threadfence();
        unsigned old = atomicAdd(&L.ctrs[1], 1u);
        islast = (old == gridDim.x - 1) ? 1 : 0;
    }
    __syncthreads();
    if (!islast) return;
    __threadfence();

    double* bsc = dpart;
    int*    bix = (int*)upart;
    double best = 1.0e300; int bidx = 0x7fffffff;
    for (int c = tid; c < NCAND; c += BLK) {
        double sc = agent_load_f64(&L.score[c]);
        if (sc < best) { best = sc; bidx = c; }       // ascending c keeps first-min
    }
    bsc[tid] = best; bix[tid] = bidx;
    __syncthreads();
    for (int s = BLK / 2; s > 0; s >>= 1) {
        if (tid < s) {
            double so = bsc[tid + s]; int io = bix[tid + s];
            if (so < bsc[tid] || (so == bsc[tid] && io < bix[tid])) { bsc[tid] = so; bix[tid] = io; }
        }
        __syncthreads();
    }
    if (tid == 0) {
        float bmin = x_min, bmax = x_max;
        if (bix[0] != 0x7fffffff) {
#pragma clang fp contract(off)
            int cand = bix[0];
            float step = rangef / 100.0f;
            int ii = cand >> 4, z = cand & 15;
            float fi = (float)(ii + 1);
            float tmp_max   = step * fi;
            float tmp_delta = tmp_max / 15.0f;
            float t = (float)z * tmp_delta;
            bmin = fmaxf(-t, x_min);
            bmax = fminf(tmp_max - t, x_max);
        }
        out[0] = bmin; out[1] = bmax;
    }
}

// ================= fallback path (round-1 proven) =================
__global__ __launch_bounds__(256) void k_params_fb(const float* __restrict__ x, int n4,
                                                   float4* __restrict__ params,
                                                   float2* __restrict__ ranges,
                                                   double* __restrict__ score,
                                                   float* __restrict__ mm) {
#pragma clang fp contract(off)
    __shared__ float smin[256], smax[256];
    const float4* x4 = (const float4*)x;
    float lmin = 3.0e38f, lmax = -3.0e38f;
    for (int i = threadIdx.x; i < n4; i += 256) {
        float4 v = x4[i];
        lmin = fminf(lmin, fminf(fminf(v.x, v.y), fminf(v.z, v.w)));
        lmax = fmaxf(lmax, fmaxf(fmaxf(v.x, v.y), fmaxf(v.z, v.w)));
    }
    smin[threadIdx.x] = lmin; smax[threadIdx.x] = lmax;
    __syncthreads();
    for (int s = 128; s > 0; s >>= 1) {
        if (threadIdx.x < s) {
            smin[threadIdx.x] = fminf(smin[threadIdx.x], smin[threadIdx.x + s]);
            smax[threadIdx.x] = fmaxf(smax[threadIdx.x], smax[threadIdx.x + s]);
        }
        __syncthreads();
    }
    float x_min = smin[0], x_max = smax[0];
    if (threadIdx.x == 0) { mm[0] = x_min; mm[1] = x_max; }
    float xrange = x_max - x_min;
    float step = xrange / 100.0f;
    for (int c = threadIdx.x; c < NCAND; c += 256) {
        int ii = c >> 4;
        int z  = c & 15;
        float fi = (float)(ii + 1);
        float tmp_max   = step * fi;
        float tmp_delta = tmp_max / 15.0f;
        float t = (float)z * tmp_delta;
        float new_min = fmaxf(-t, x_min);
        float new_max = fminf(tmp_max - t, x_max);
        float min_neg = fminf(new_min, 0.0f);
        float max_pos = fmaxf(new_max, 0.0f);
        float scale = fmaxf((max_pos - min_neg) / 15.0f, F32_EPS);
        float zp = 0.0f - rintf(min_neg / scale);
        zp = fminf(fmaxf(zp, 0.0f), 15.0f);
        float inv = (float)(1.0 / (double)scale);
        params[c] = make_float4(scale, inv, 0.0f - zp, 15.0f - zp);
        ranges[c] = make_float2(new_min, new_max);
        score[c]  = 0.0;
    }
}

__global__ __launch_bounds__(256) void k_score_bf(const float* __restrict__ x, int n4,
                                                  const float4* __restrict__ params,
                                                  double* __restrict__ score) {
    const int tid = blockIdx.x * 256 + threadIdx.x;
    const int T = gridDim.x * 256;
    const float4* x4 = (const float4*)x;
    float xs[16];
    #pragma unroll
    for (int k = 0; k < 4; k++) {
        int i4 = tid + k * T;
        float4 v;
        if (i4 < n4) v = x4[i4];
        else { v.x = 0.0f; v.y = 0.0f; v.z = 0.0f; v.w = 0.0f; }
        xs[4*k+0] = v.x; xs[4*k+1] = v.y; xs[4*k+2] = v.z; xs[4*k+3] = v.w;
    }
    int c = (int)((blockIdx.x * 37u) % NCAND);
    for (int k = 0; k < NCAND; k++) {
        float4 p = params[c];
        float s   = rfl_f(p.x);
        float inv = rfl_f(p.y);
        float lo  = rfl_f(p.z);
        float hi  = rfl_f(p.w);
        float acc = 0.0f;
        #pragma unroll
        for (int e = 0; e < 16; e++) {
            float r = rintf(xs[e] * inv);
            r = fminf(fmaxf(r, lo), hi);
            float d = fmaf(r, s, -xs[e]);
            acc = fmaf(d, d, acc);
        }
        #pragma unroll
        for (int off = 32; off > 0; off >>= 1)
            acc += __shfl_xor(acc, off);
        if ((threadIdx.x & 63) == 0)
            atomicAdd(&score[c], (double)acc);
        c++; if (c >= NCAND) c -= NCAND;
    }
}

__global__ void k_final_fb(const double* __restrict__ score,
                           const float2* __restrict__ ranges,
                           const float* __restrict__ mm,
                           float* __restrict__ out) {
    if (blockIdx.x == 0 && threadIdx.x == 0) {
        double best = 1.0e300;
        float bmin = mm[0], bmax = mm[1];
        for (int c = 0; c < NCAND; c++) {
            double sc = score[c];
            if (sc < best) { best = sc; bmin = ranges[c].x; bmax = ranges[c].y; }
        }
        out[0] = bmin;
        out[1] = bmax;
    }
}

extern "C" void kernel_launch(void* const* d_in, const int* in_sizes, int n_in,
                              void* d_out, int out_size, void* d_ws, size_t ws_size,
                              hipStream_t stream) {
    const float* x = (const float*)d_in[0];
    int n  = in_sizes[0];          // 4194304
    int n4 = n / 4;
    float* out = (float*)d_out;
    WSL L = make_ws((char*)d_ws);

    int per4 = (n4 + G2 - 1) / G2;
    bool ok = (ws_size >= L.small_needed) && ((n % 4) == 0) && (per4 * 4 <= SLICE) && (n4 > 0);

    if (ok) {
        hipMemsetAsync(d_ws, 0, 64, stream);             // ticket/barrier counters only
        k_fused<<<G2, BLK, 0, stream>>>(x, n4, (char*)d_ws, out);
    } else if (ws_size >= L.small_needed) {
        k_params_fb<<<1, 256, 0, stream>>>(x, n4, L.params, L.ranges, L.scoreFB, L.mm);
        int blocks = ((n4 + 3) / 4 + 255) / 256;
        k_score_bf<<<blocks, 256, 0, stream>>>(x, n4, L.params, L.scoreFB);
        k_final_fb<<<1, 64, 0, stream>>>(L.scoreFB, L.ranges, L.mm, out);
    }
}

// Round 12
// 129.695 us; speedup vs baseline: 1.1082x; 1.1082x over previous
//
#include <hip/hip_runtime.h>
#include <math.h>

#define NUM_I 100
#define NZ    16
#define NCAND (NUM_I * NZ)     // 1600
#define NBL   8192             // local LDS bins (value-linear over global [min,max])
#define G2    256              // main grid: 1 block/CU -> all co-resident (gbar-safe)
#define BLK   1024             // 16 waves/block -> 16 waves/CU
#define SLICE 16384            // elements per block
#define BPT   (NBL / BLK)      // 8 bins per thread
#define F32_EPS 1.1920928955078125e-07f
#define AGENT __HIP_MEMORY_SCOPE_AGENT

// ---------------- workspace layout ----------------
struct WSL {
    unsigned* ctrs;            // 16 slots ([0]=gbar, [1]=final ticket) -- memset 64 B
    double*   score;           // 1600 cells (zeroed in-kernel pre-gbar0; shifted by -sum(x^2))
    float*    pmin; float* pmax;           // G2 partials
    float4*   params; float2* ranges; float* mm;   // fallback path only
    double*   scoreFB;
    size_t    small_needed;
};

__host__ __device__ static inline WSL make_ws(char* w0) {
    WSL L; char* w = w0;
    L.ctrs   = (unsigned*)w; w += 64;
    L.score  = (double*)w;   w += sizeof(double) * NCAND;
    L.pmin   = (float*)w;    w += sizeof(float) * G2;
    L.pmax   = (float*)w;    w += sizeof(float) * G2;
    L.params = (float4*)w;   w += sizeof(float4) * NCAND;
    L.ranges = (float2*)w;   w += sizeof(float2) * NCAND;
    L.mm     = (float*)w;    w += sizeof(float) * 4;
    size_t head = (size_t)(w - w0);
    L.small_needed = (head + 15) & ~(size_t)15;
    L.scoreFB = L.score;
    return L;
}

// ---------------- device helpers ----------------
static __device__ __forceinline__ float rfl_f(float v) {
    return __int_as_float(__builtin_amdgcn_readfirstlane(__float_as_int(v)));
}
static __device__ __forceinline__ double agent_load_f64(const double* p) {
    return __hip_atomic_load(p, __ATOMIC_RELAXED, AGENT);
}
// monotone value->local-bin map, shared by elements and thresholds (exactness
// needs only monotonicity: bin(v)<bin(t) => v<t ; bin(v)>bin(t) => v>=t).
static __device__ __forceinline__ int bin_loc(float v, float lo, float invw) {
    int b = (int)floorf((v - lo) * invw);
    return min(max(b, 0), NBL - 1);
}
// round-6/8-proven global barrier (tid0-only cache maintenance; all blocks co-resident)
static __device__ __forceinline__ void gbar(unsigned* ctr, int nblk) {
    __syncthreads();
    if (threadIdx.x == 0) {
        __hip_atomic_fetch_add(ctr, 1u, __ATOMIC_ACQ_REL, AGENT);
        while (__hip_atomic_load(ctr, __ATOMIC_RELAXED, AGENT) < (unsigned)nblk)
            __builtin_amdgcn_s_sleep(8);
        (void)__hip_atomic_load(ctr, __ATOMIC_ACQUIRE, AGENT);
    }
    __syncthreads();
}

// ============ the fused kernel: minmax -> gbar -> local sort+moments -> scores -> argmin ============
__global__ __launch_bounds__(BLK, 4) void k_fused(const float* __restrict__ x, int n4,
                                                  char* wsbase, float* __restrict__ out) {
    WSL L = make_ws(wsbase);
    __shared__ __align__(16) float ssort[SLICE];       // 64 KB  locally binned slice
    __shared__ __align__(8) unsigned short Cs[NBL + 2];//  16 KB  u16 exclusive bin starts [0..NBL]
    __shared__ __align__(16) double S1p[NBL];          // 64 KB  bin sum(x) -> excl prefix
    __shared__ double   dpart[BLK];                    //  8 KB scratch (f64 scan / argmin / f32 minmax)
    __shared__ unsigned upart[BLK];                    //  4 KB scratch (u32 scan / argmin idx)
    __shared__ double   stot[1];
    __shared__ float    sxm[2];
    __shared__ int      islast;
    // u32 hist/cursor aliased onto S1p's first 32 KB (S1p dead until Ph F1)
    unsigned* Htmp = (unsigned*)S1p;
    const int tid = threadIdx.x, blk = blockIdx.x;
    const float4* x4 = (const float4*)x;
    const int per4 = (n4 + G2 - 1) / G2;
    const int beg4 = blk * per4, end4 = min(beg4 + per4, n4);
    const int len = (end4 > beg4) ? (end4 - beg4) * 4 : 0;

    // ---- Ph A: zero score slice + block min/max partial over own slice ----
    {
        int gtid = blk * BLK + tid;
        if (gtid < NCAND) L.score[gtid] = 0.0;     // published by gbar0
        float* rmin = (float*)dpart; float* rmax = rmin + BLK;   // 8 KB = dpart
        float lmin = 3.0e38f, lmax = -3.0e38f;
        for (int i = beg4 + tid; i < end4; i += BLK) {
            float4 v = x4[i];
            lmin = fminf(lmin, fminf(fminf(v.x, v.y), fminf(v.z, v.w)));
            lmax = fmaxf(lmax, fmaxf(fmaxf(v.x, v.y), fmaxf(v.z, v.w)));
        }
        rmin[tid] = lmin; rmax[tid] = lmax;
        __syncthreads();
        for (int s = BLK / 2; s > 0; s >>= 1) {
            if (tid < s) {
                rmin[tid] = fminf(rmin[tid], rmin[tid + s]);
                rmax[tid] = fmaxf(rmax[tid], rmax[tid + s]);
            }
            __syncthreads();
        }
        if (tid == 0) { L.pmin[blk] = rmin[0]; L.pmax[blk] = rmax[0]; }
    }
    gbar(&L.ctrs[0], G2);    // publishes pmin/pmax + zeroed score

    // ---- Ph B: every block redundantly reduces partials (identical order => identical result) ----
    {
        float* rmin = (float*)dpart; float* rmax = rmin + BLK;
        float lmin = (tid < G2) ? L.pmin[tid] : 3.0e38f;
        float lmax = (tid < G2) ? L.pmax[tid] : -3.0e38f;
        rmin[tid] = lmin; rmax[tid] = lmax;
        __syncthreads();
        for (int s = BLK / 2; s > 0; s >>= 1) {
            if (tid < s) {
                rmin[tid] = fminf(rmin[tid], rmin[tid + s]);
                rmax[tid] = fmaxf(rmax[tid], rmax[tid + s]);
            }
            __syncthreads();
        }
        if (tid == 0) { sxm[0] = rmin[0]; sxm[1] = rmax[0]; }
        __syncthreads();
    }
    const float x_min = sxm[0], x_max = sxm[1];
    const float rangef = x_max - x_min;
    const float lo = x_min;
    const float invw = (rangef > 0.0f) ? ((float)NBL / rangef) : 0.0f;

    if (len > 0) {
        // ---- Ph C: local histogram into u32 Htmp ----
        for (int b = tid; b < NBL; b += BLK) Htmp[b] = 0u;
        __syncthreads();
        for (int i = beg4 + tid; i < end4; i += BLK) {
            float4 v = x4[i];
            atomicAdd(&Htmp[bin_loc(v.x, lo, invw)], 1u);
            atomicAdd(&Htmp[bin_loc(v.y, lo, invw)], 1u);
            atomicAdd(&Htmp[bin_loc(v.z, lo, invw)], 1u);
            atomicAdd(&Htmp[bin_loc(v.w, lo, invw)], 1u);
        }
        __syncthreads();
        // ---- Ph D: exclusive prefix of counts -> u16 starts Cs + u32 cursor Htmp ----
        unsigned cl[BPT]; unsigned ps = 0;
        #pragma unroll
        for (int k = 0; k < BPT; k++) { cl[k] = Htmp[tid * BPT + k]; ps += cl[k]; }
        upart[tid] = ps;
        __syncthreads();
        for (int off = 1; off < BLK; off <<= 1) {
            unsigned v = (tid >= off) ? upart[tid - off] : 0u;
            __syncthreads();
            upart[tid] += v;
            __syncthreads();
        }
        unsigned run = upart[tid] - ps;
        #pragma unroll
        for (int k = 0; k < BPT; k++) {
            int b = tid * BPT + k;
            Cs[b] = (unsigned short)run;       // start (<= 16384, fits u16)
            Htmp[b] = run;                     // scatter cursor (u32, atomically bumped)
            run += cl[k];
        }
        if (tid == BLK - 1) Cs[NBL] = (unsigned short)run;   // == len
        __syncthreads();
        // ---- Ph E: scatter into LDS via u32 cursors ----
        for (int i = beg4 + tid; i < end4; i += BLK) {
            float4 v = x4[i];
            unsigned p;
            p = atomicAdd(&Htmp[bin_loc(v.x, lo, invw)], 1u); ssort[p] = v.x;
            p = atomicAdd(&Htmp[bin_loc(v.y, lo, invw)], 1u); ssort[p] = v.y;
            p = atomicAdd(&Htmp[bin_loc(v.z, lo, invw)], 1u); ssort[p] = v.z;
            p = atomicAdd(&Htmp[bin_loc(v.w, lo, invw)], 1u); ssort[p] = v.w;
        }
        __syncthreads();
        // ---- Ph F1: per-bin sum(x), STRIDED bin assignment (clobbers Htmp -- dead now) ----
        for (int k = 0; k < BPT; k++) {
            int b = tid + k * BLK;
            unsigned st = Cs[b], en = Cs[b + 1];
            double s1 = 0.0;
            for (unsigned i = st; i < en; i++) s1 += (double)ssort[i];
            S1p[b] = s1;                   // temporarily per-bin sums
        }
        __syncthreads();
        // ---- Ph F2: exclusive prefix of sums (contiguous BPT bins/thread) ----
        double l1[BPT];
        double a1 = 0.0;
        #pragma unroll
        for (int k = 0; k < BPT; k++) { l1[k] = S1p[tid * BPT + k]; a1 += l1[k]; }
        dpart[tid] = a1;
        __syncthreads();
        for (int off = 1; off < BLK; off <<= 1) {
            double v1 = (tid >= off) ? dpart[tid - off] : 0.0;
            __syncthreads();
            dpart[tid] += v1;
            __syncthreads();
        }
        double b1 = dpart[tid] - a1;
        #pragma unroll
        for (int k = 0; k < BPT; k++) {
            int b = tid * BPT + k;
            S1p[b] = b1; b1 += l1[k];
        }
        if (tid == BLK - 1) stot[0] = dpart[BLK - 1];
        __syncthreads();

        // ---- Ph G: local partial score (round-10-proven form; shifted by -sum(x^2)) ----
        const double totS1 = stot[0];
        for (int q = 0; q < (NCAND + BLK - 1) / BLK; q++) {
            int cand = q * BLK + ((tid + blk) & (BLK - 1));   // stagger atomic targets
            if (cand >= NCAND) continue;
            int zi; double sd;
            {
#pragma clang fp contract(off)
                float step = rangef / 100.0f;
                int ii = cand >> 4, z = cand & 15;
                float fi = (float)(ii + 1);
                float tmp_max   = step * fi;
                float tmp_delta = tmp_max / 15.0f;
                float t = (float)z * tmp_delta;
                float new_min = fmaxf(-t, x_min);
                float new_max = fminf(tmp_max - t, x_max);
                float min_neg = fminf(new_min, 0.0f);
                float max_pos = fmaxf(new_max, 0.0f);
                float scale = fmaxf((max_pos - min_neg) / 15.0f, F32_EPS);
                float zp = 0.0f - rintf(min_neg / scale);
                zp = fminf(fmaxf(zp, 0.0f), 15.0f);
                zi = (int)zp; sd = (double)scale;
            }
            double prevC = 0.0, prev1 = 0.0, sc = 0.0;
            for (int j = 0; j <= 15; j++) {
                double Cc, C1;
                if (j < 15) {
                    double td = ((double)(j - zi) + 0.5) * sd;
                    float tf = (float)td;
                    int bf = bin_loc(tf, lo, invw);
                    unsigned st = Cs[bf], en = Cs[bf + 1];
                    unsigned cnt = 0; double s1 = 0.0;
                    unsigned i = st;
                    for (; i < en && (i & 3u); i++) {               // align head
                        float v = ssort[i];
                        if (v < tf) { cnt++; s1 += (double)v; }
                    }
                    for (; i + 4u <= en; i += 4u) {                 // ds_read_b128 body
                        float4 v4 = *reinterpret_cast<const float4*>(&ssort[i]);
                        float m0 = (v4.x < tf) ? v4.x : 0.0f;
                        float m1 = (v4.y < tf) ? v4.y : 0.0f;
                        float m2 = (v4.z < tf) ? v4.z : 0.0f;
                        float m3 = (v4.w < tf) ? v4.w : 0.0f;
                        cnt += (v4.x < tf); cnt += (v4.y < tf);
                        cnt += (v4.z < tf); cnt += (v4.w < tf);
                        s1 += (double)((m0 + m1) + (m2 + m3));
                    }
                    for (; i < en; i++) {                           // tail
                        float v = ssort[i];
                        if (v < tf) { cnt++; s1 += (double)v; }
                    }
                    Cc = (double)st + (double)cnt;
                    C1 = S1p[bf] + s1;
                } else {
                    Cc = (double)len; C1 = totS1;
                }
                double ms = (double)(j - zi) * sd;
                sc += ms * (ms * (Cc - prevC) - 2.0 * (C1 - prev1));
                prevC = Cc; prev1 = C1;
            }
            atomicAdd(&L.score[cand], sc);            // device-scope fp64
        }
    }

    // ---- Ph H: last-block ticket + argmin (round-7-proven pattern) ----
    __syncthreads();
    if (tid == 0) {
        __threadfence();
        unsigned old = atomicAdd(&L.ctrs[1], 1u);
        islast = (old == gridDim.x - 1) ? 1 : 0;
    }
    __syncthreads();
    if (!islast) return;
    __threadfence();

    double* bsc = dpart;
    int*    bix = (int*)upart;
    double best = 1.0e300; int bidx = 0x7fffffff;
    for (int c = tid; c < NCAND; c += BLK) {
        double sc = agent_load_f64(&L.score[c]);
        if (sc < best) { best = sc; bidx = c; }       // ascending c keeps first-min
    }
    bsc[tid] = best; bix[tid] = bidx;
    __syncthreads();
    for (int s = BLK / 2; s > 0; s >>= 1) {
        if (tid < s) {
            double so = bsc[tid + s]; int io = bix[tid + s];
            if (so < bsc[tid] || (so == bsc[tid] && io < bix[tid])) { bsc[tid] = so; bix[tid] = io; }
        }
        __syncthreads();
    }
    if (tid == 0) {
        float bmin = x_min, bmax = x_max;
        if (bix[0] != 0x7fffffff) {
#pragma clang fp contract(off)
            int cand = bix[0];
            float step = rangef / 100.0f;
            int ii = cand >> 4, z = cand & 15;
            float fi = (float)(ii + 1);
            float tmp_max   = step * fi;
            float tmp_delta = tmp_max / 15.0f;
            float t = (float)z * tmp_delta;
            bmin = fmaxf(-t, x_min);
            bmax = fminf(tmp_max - t, x_max);
        }
        out[0] = bmin; out[1] = bmax;
    }
}

// ================= fallback path (round-1 proven) =================
__global__ __launch_bounds__(256) void k_params_fb(const float* __restrict__ x, int n4,
                                                   float4* __restrict__ params,
                                                   float2* __restrict__ ranges,
                                                   double* __restrict__ score,
                                                   float* __restrict__ mm) {
#pragma clang fp contract(off)
    __shared__ float smin[256], smax[256];
    const float4* x4 = (const float4*)x;
    float lmin = 3.0e38f, lmax = -3.0e38f;
    for (int i = threadIdx.x; i < n4; i += 256) {
        float4 v = x4[i];
        lmin = fminf(lmin, fminf(fminf(v.x, v.y), fminf(v.z, v.w)));
        lmax = fmaxf(lmax, fmaxf(fmaxf(v.x, v.y), fmaxf(v.z, v.w)));
    }
    smin[threadIdx.x] = lmin; smax[threadIdx.x] = lmax;
    __syncthreads();
    for (int s = 128; s > 0; s >>= 1) {
        if (threadIdx.x < s) {
            smin[threadIdx.x] = fminf(smin[threadIdx.x], smin[threadIdx.x + s]);
            smax[threadIdx.x] = fmaxf(smax[threadIdx.x], smax[threadIdx.x + s]);
        }
        __syncthreads();
    }
    float x_min = smin[0], x_max = smax[0];
    if (threadIdx.x == 0) { mm[0] = x_min; mm[1] = x_max; }
    float xrange = x_max - x_min;
    float step = xrange / 100.0f;
    for (int c = threadIdx.x; c < NCAND; c += 256) {
        int ii = c >> 4;
        int z  = c & 15;
        float fi = (float)(ii + 1);
        float tmp_max   = step * fi;
        float tmp_delta = tmp_max / 15.0f;
        float t = (float)z * tmp_delta;
        float new_min = fmaxf(-t, x_min);
        float new_max = fminf(tmp_max - t, x_max);
        float min_neg = fminf(new_min, 0.0f);
        float max_pos = fmaxf(new_max, 0.0f);
        float scale = fmaxf((max_pos - min_neg) / 15.0f, F32_EPS);
        float zp = 0.0f - rintf(min_neg / scale);
        zp = fminf(fmaxf(zp, 0.0f), 15.0f);
        float inv = (float)(1.0 / (double)scale);
        params[c] = make_float4(scale, inv, 0.0f - zp, 15.0f - zp);
        ranges[c] = make_float2(new_min, new_max);
        score[c]  = 0.0;
    }
}

__global__ __launch_bounds__(256) void k_score_bf(const float* __restrict__ x, int n4,
                                                  const float4* __restrict__ params,
                                                  double* __restrict__ score) {
    const int tid = blockIdx.x * 256 + threadIdx.x;
    const int T = gridDim.x * 256;
    const float4* x4 = (const float4*)x;
    float xs[16];
    #pragma unroll
    for (int k = 0; k < 4; k++) {
        int i4 = tid + k * T;
        float4 v;
        if (i4 < n4) v = x4[i4];
        else { v.x = 0.0f; v.y = 0.0f; v.z = 0.0f; v.w = 0.0f; }
        xs[4*k+0] = v.x; xs[4*k+1] = v.y; xs[4*k+2] = v.z; xs[4*k+3] = v.w;
    }
    int c = (int)((blockIdx.x * 37u) % NCAND);
    for (int k = 0; k < NCAND; k++) {
        float4 p = params[c];
        float s   = rfl_f(p.x);
        float inv = rfl_f(p.y);
        float lo  = rfl_f(p.z);
        float hi  = rfl_f(p.w);
        float acc = 0.0f;
        #pragma unroll
        for (int e = 0; e < 16; e++) {
            float r = rintf(xs[e] * inv);
            r = fminf(fmaxf(r, lo), hi);
            float d = fmaf(r, s, -xs[e]);
            acc = fmaf(d, d, acc);
        }
        #pragma unroll
        for (int off = 32; off > 0; off >>= 1)
            acc += __shfl_xor(acc, off);
        if ((threadIdx.x & 63) == 0)
            atomicAdd(&score[c], (double)acc);
        c++; if (c >= NCAND) c -= NCAND;
    }
}

__global__ void k_final_fb(const double* __restrict__ score,
                           const float2* __restrict__ ranges,
                           const float* __restrict__ mm,
                           float* __restrict__ out) {
    if (blockIdx.x == 0 && threadIdx.x == 0) {
        double best = 1.0e300;
        float bmin = mm[0], bmax = mm[1];
        for (int c = 0; c < NCAND; c++) {
            double sc = score[c];
            if (sc < best) { best = sc; bmin = ranges[c].x; bmax = ranges[c].y; }
        }
        out[0] = bmin;
        out[1] = bmax;
    }
}

extern "C" void kernel_launch(void* const* d_in, const int* in_sizes, int n_in,
                              void* d_out, int out_size, void* d_ws, size_t ws_size,
                              hipStream_t stream) {
    const float* x = (const float*)d_in[0];
    int n  = in_sizes[0];          // 4194304
    int n4 = n / 4;
    float* out = (float*)d_out;
    WSL L = make_ws((char*)d_ws);

    int per4 = (n4 + G2 - 1) / G2;
    bool ok = (ws_size >= L.small_needed) && ((n % 4) == 0) && (per4 * 4 <= SLICE) && (n4 > 0);

    if (ok) {
        hipMemsetAsync(d_ws, 0, 64, stream);             // ticket/barrier counters only
        k_fused<<<G2, BLK, 0, stream>>>(x, n4, (char*)d_ws, out);
    } else if (ws_size >= L.small_needed) {
        k_params_fb<<<1, 256, 0, stream>>>(x, n4, L.params, L.ranges, L.scoreFB, L.mm);
        int blocks = ((n4 + 3) / 4 + 255) / 256;
        k_score_bf<<<blocks, 256, 0, stream>>>(x, n4, L.params, L.scoreFB);
        k_final_fb<<<1, 64, 0, stream>>>(L.scoreFB, L.ranges, L.mm, out);
    }
}

// Round 13
// 125.874 us; speedup vs baseline: 1.1418x; 1.0304x over previous
//
#include <hip/hip_runtime.h>
#include <math.h>

#define NUM_I 100
#define NZ    16
#define NCAND (NUM_I * NZ)     // 1600
#define NBL   8192             // local LDS bins (value-linear over global [min,max])
#define G2    256              // main grid: 1 block/CU -> all co-resident (gbar-safe)
#define BLK   1024             // 16 waves/block -> 16 waves/CU
#define SLICE 16384            // elements per block
#define EPT   16               // elements per thread (register-resident slice)
#define LPT   4                // float4 loads per thread
#define BPT   (NBL / BLK)      // 8 bins per thread
#define F32_EPS 1.1920928955078125e-07f
#define AGENT __HIP_MEMORY_SCOPE_AGENT

// ---------------- workspace layout ----------------
struct WSL {
    unsigned* ctrs;            // 16 slots ([0]=gbar, [1]=final ticket) -- memset 64 B
    double*   score;           // 1600 cells (zeroed in-kernel pre-gbar0; shifted by -sum(x^2))
    float*    pmin; float* pmax;           // G2 partials
    float4*   params; float2* ranges; float* mm;   // fallback path only
    double*   scoreFB;
    size_t    small_needed;
};

__host__ __device__ static inline WSL make_ws(char* w0) {
    WSL L; char* w = w0;
    L.ctrs   = (unsigned*)w; w += 64;
    L.score  = (double*)w;   w += sizeof(double) * NCAND;
    L.pmin   = (float*)w;    w += sizeof(float) * G2;
    L.pmax   = (float*)w;    w += sizeof(float) * G2;
    L.params = (float4*)w;   w += sizeof(float4) * NCAND;
    L.ranges = (float2*)w;   w += sizeof(float2) * NCAND;
    L.mm     = (float*)w;    w += sizeof(float) * 4;
    size_t head = (size_t)(w - w0);
    L.small_needed = (head + 15) & ~(size_t)15;
    L.scoreFB = L.score;
    return L;
}

// ---------------- device helpers ----------------
static __device__ __forceinline__ float rfl_f(float v) {
    return __int_as_float(__builtin_amdgcn_readfirstlane(__float_as_int(v)));
}
static __device__ __forceinline__ double agent_load_f64(const double* p) {
    return __hip_atomic_load(p, __ATOMIC_RELAXED, AGENT);
}
// monotone value->local-bin map, shared by elements and thresholds (exactness
// needs only monotonicity: bin(v)<bin(t) => v<t ; bin(v)>bin(t) => v>=t).
static __device__ __forceinline__ int bin_loc(float v, float lo, float invw) {
    int b = (int)floorf((v - lo) * invw);
    return min(max(b, 0), NBL - 1);
}
// round-6/8-proven global barrier (tid0-only cache maintenance; all blocks co-resident)
static __device__ __forceinline__ void gbar(unsigned* ctr, int nblk) {
    __syncthreads();
    if (threadIdx.x == 0) {
        __hip_atomic_fetch_add(ctr, 1u, __ATOMIC_ACQ_REL, AGENT);
        while (__hip_atomic_load(ctr, __ATOMIC_RELAXED, AGENT) < (unsigned)nblk)
            __builtin_amdgcn_s_sleep(8);
        (void)__hip_atomic_load(ctr, __ATOMIC_ACQUIRE, AGENT);
    }
    __syncthreads();
}

// ============ the fused kernel ============
__global__ __launch_bounds__(BLK, 4) void k_fused(const float* __restrict__ x, int n4,
                                                  char* wsbase, float* __restrict__ out) {
    WSL L = make_ws(wsbase);
    __shared__ __align__(16) float ssort[SLICE];        // 64 KB  locally binned slice
    __shared__ __align__(8) unsigned short Cs[NBL + 2]; // 16 KB  u16 exclusive bin starts [0..NBL]
    __shared__ __align__(16) double S1p[NBL];           // 64 KB  bin sum(x) -> excl prefix
    __shared__ unsigned wsu[16];                        // cross-wave scan/argmin scratch
    __shared__ double   wsd[16];
    __shared__ float    wminf[16], wmaxf[16];
    __shared__ double   stot[1];
    __shared__ float    sxm[2];
    __shared__ int      islast;
    // u32 hist/cursor aliased onto S1p's first 32 KB (S1p dead until Ph F1)
    unsigned* Htmp = (unsigned*)S1p;
    const int tid = threadIdx.x, blk = blockIdx.x;
    const int lane = tid & 63, wv = tid >> 6;
    const float4* x4 = (const float4*)x;
    const int per4 = (n4 + G2 - 1) / G2;
    const int beg4 = blk * per4, end4 = min(beg4 + per4, n4);
    const int len = (end4 > beg4) ? (end4 - beg4) * 4 : 0;

    // ---- Ph A: zero score slice + register-load slice + wave-reduce min/max ----
    float xs[EPT];
    {
        int gtid = blk * BLK + tid;
        if (gtid < NCAND) L.score[gtid] = 0.0;     // published by gbar0
        float lmin = 3.0e38f, lmax = -3.0e38f;
        #pragma unroll
        for (int k = 0; k < LPT; k++) {
            int i = beg4 + tid + k * BLK;
            float4 v;
            if (i < end4) {
                v = x4[i];
                lmin = fminf(lmin, fminf(fminf(v.x, v.y), fminf(v.z, v.w)));
                lmax = fmaxf(lmax, fmaxf(fmaxf(v.x, v.y), fmaxf(v.z, v.w)));
            } else { v.x = 0.0f; v.y = 0.0f; v.z = 0.0f; v.w = 0.0f; }
            xs[4*k+0] = v.x; xs[4*k+1] = v.y; xs[4*k+2] = v.z; xs[4*k+3] = v.w;
        }
        #pragma unroll
        for (int off = 32; off > 0; off >>= 1) {
            lmin = fminf(lmin, __shfl_xor(lmin, off));
            lmax = fmaxf(lmax, __shfl_xor(lmax, off));
        }
        if (lane == 0) { wminf[wv] = lmin; wmaxf[wv] = lmax; }
        __syncthreads();
        if (tid == 0) {
            float a = wminf[0], b = wmaxf[0];
            for (int k = 1; k < 16; k++) { a = fminf(a, wminf[k]); b = fmaxf(b, wmaxf[k]); }
            L.pmin[blk] = a; L.pmax[blk] = b;
        }
    }
    gbar(&L.ctrs[0], G2);    // publishes pmin/pmax + zeroed score

    // ---- Ph B: every block redundantly reduces the 256 partials ----
    {
        float lmin = (tid < G2) ? L.pmin[tid] : 3.0e38f;
        float lmax = (tid < G2) ? L.pmax[tid] : -3.0e38f;
        #pragma unroll
        for (int off = 32; off > 0; off >>= 1) {
            lmin = fminf(lmin, __shfl_xor(lmin, off));
            lmax = fmaxf(lmax, __shfl_xor(lmax, off));
        }
        if (lane == 0) { wminf[wv] = lmin; wmaxf[wv] = lmax; }
        __syncthreads();
        if (tid == 0) {
            float a = wminf[0], b = wmaxf[0];
            for (int k = 1; k < 16; k++) { a = fminf(a, wminf[k]); b = fmaxf(b, wmaxf[k]); }
            sxm[0] = a; sxm[1] = b;
        }
        __syncthreads();
    }
    const float x_min = sxm[0], x_max = sxm[1];
    const float rangef = x_max - x_min;
    const float lo = x_min;
    const float invw = (rangef > 0.0f) ? ((float)NBL / rangef) : 0.0f;

    if (len > 0) {
        // precompute bins once (register-resident)
        unsigned short bins[EPT];
        #pragma unroll
        for (int e = 0; e < EPT; e++) bins[e] = (unsigned short)bin_loc(xs[e], lo, invw);

        // ---- Ph C: local histogram into u32 Htmp (from registers) ----
        for (int b = tid; b < NBL; b += BLK) Htmp[b] = 0u;
        __syncthreads();
        #pragma unroll
        for (int k = 0; k < LPT; k++) {
            if (beg4 + tid + k * BLK < end4) {
                atomicAdd(&Htmp[bins[4*k+0]], 1u);
                atomicAdd(&Htmp[bins[4*k+1]], 1u);
                atomicAdd(&Htmp[bins[4*k+2]], 1u);
                atomicAdd(&Htmp[bins[4*k+3]], 1u);
            }
        }
        __syncthreads();
        // ---- Ph D: shuffle-based exclusive block scan -> u16 starts Cs + u32 cursor Htmp ----
        {
            unsigned cl[BPT]; unsigned ps = 0;
            #pragma unroll
            for (int k = 0; k < BPT; k++) { cl[k] = Htmp[tid * BPT + k]; ps += cl[k]; }
            unsigned incl = ps;
            #pragma unroll
            for (int off = 1; off < 64; off <<= 1) {
                unsigned t = __shfl_up(incl, off);
                if (lane >= off) incl += t;
            }
            if (lane == 63) wsu[wv] = incl;
            __syncthreads();
            if (wv == 0 && lane < 16) {
                unsigned w = wsu[lane], wi = w;
                #pragma unroll
                for (int off = 1; off < 16; off <<= 1) {
                    unsigned t = __shfl_up(wi, off);
                    if (lane >= off) wi += t;
                }
                wsu[lane] = wi - w;                   // exclusive wave offsets
            }
            __syncthreads();
            unsigned run = wsu[wv] + incl - ps;       // exclusive base for this thread
            #pragma unroll
            for (int k = 0; k < BPT; k++) {
                int b = tid * BPT + k;
                Cs[b] = (unsigned short)run;          // start (<=16384, fits u16)
                Htmp[b] = run;                        // scatter cursor
                run += cl[k];
            }
            if (tid == BLK - 1) Cs[NBL] = (unsigned short)run;   // == len
            __syncthreads();
        }
        // ---- Ph E: scatter into LDS via u32 cursors (from registers) ----
        #pragma unroll
        for (int k = 0; k < LPT; k++) {
            if (beg4 + tid + k * BLK < end4) {
                unsigned p;
                p = atomicAdd(&Htmp[bins[4*k+0]], 1u); ssort[p] = xs[4*k+0];
                p = atomicAdd(&Htmp[bins[4*k+1]], 1u); ssort[p] = xs[4*k+1];
                p = atomicAdd(&Htmp[bins[4*k+2]], 1u); ssort[p] = xs[4*k+2];
                p = atomicAdd(&Htmp[bins[4*k+3]], 1u); ssort[p] = xs[4*k+3];
            }
        }
        __syncthreads();
        // ---- Ph F1: per-bin sum(x), STRIDED bin assignment (clobbers Htmp -- dead now) ----
        for (int k = 0; k < BPT; k++) {
            int b = tid + k * BLK;
            unsigned st = Cs[b], en = Cs[b + 1];
            double s1 = 0.0;
            for (unsigned i = st; i < en; i++) s1 += (double)ssort[i];
            S1p[b] = s1;                   // temporarily per-bin sums
        }
        __syncthreads();
        // ---- Ph F2: shuffle-based exclusive f64 prefix of sums ----
        {
            double l1[BPT]; double a1 = 0.0;
            #pragma unroll
            for (int k = 0; k < BPT; k++) { l1[k] = S1p[tid * BPT + k]; a1 += l1[k]; }
            double incl = a1;
            #pragma unroll
            for (int off = 1; off < 64; off <<= 1) {
                double t = __shfl_up(incl, off);
                if (lane >= off) incl += t;
            }
            if (lane == 63) wsd[wv] = incl;
            __syncthreads();
            if (wv == 0 && lane < 16) {
                double w = wsd[lane], wi = w;
                #pragma unroll
                for (int off = 1; off < 16; off <<= 1) {
                    double t = __shfl_up(wi, off);
                    if (lane >= off) wi += t;
                }
                wsd[lane] = wi - w;
            }
            __syncthreads();
            double b1 = wsd[wv] + incl - a1;
            #pragma unroll
            for (int k = 0; k < BPT; k++) {
                int b = tid * BPT + k;
                S1p[b] = b1; b1 += l1[k];
            }
            if (tid == BLK - 1) stot[0] = b1;         // total sum(x) of slice
            __syncthreads();
        }

        // ---- Ph G: local partial score (round-10-proven form; shifted by -sum(x^2)) ----
        const double totS1 = stot[0];
        for (int q = 0; q < (NCAND + BLK - 1) / BLK; q++) {
            int cand = q * BLK + ((tid + blk) & (BLK - 1));   // stagger atomic targets
            if (cand >= NCAND) continue;
            int zi; double sd;
            {
#pragma clang fp contract(off)
                float step = rangef / 100.0f;
                int ii = cand >> 4, z = cand & 15;
                float fi = (float)(ii + 1);
                float tmp_max   = step * fi;
                float tmp_delta = tmp_max / 15.0f;
                float t = (float)z * tmp_delta;
                float new_min = fmaxf(-t, x_min);
                float new_max = fminf(tmp_max - t, x_max);
                float min_neg = fminf(new_min, 0.0f);
                float max_pos = fmaxf(new_max, 0.0f);
                float scale = fmaxf((max_pos - min_neg) / 15.0f, F32_EPS);
                float zp = 0.0f - rintf(min_neg / scale);
                zp = fminf(fmaxf(zp, 0.0f), 15.0f);
                zi = (int)zp; sd = (double)scale;
            }
            double prevC = 0.0, prev1 = 0.0, sc = 0.0;
            for (int j = 0; j <= 15; j++) {
                double Cc, C1;
                if (j < 15) {
                    double td = ((double)(j - zi) + 0.5) * sd;
                    float tf = (float)td;
                    int bf = bin_loc(tf, lo, invw);
                    unsigned st = Cs[bf], en = Cs[bf + 1];
                    unsigned cnt = 0; double s1 = 0.0;
                    unsigned i = st;
                    for (; i < en && (i & 3u); i++) {               // align head
                        float v = ssort[i];
                        if (v < tf) { cnt++; s1 += (double)v; }
                    }
                    for (; i + 4u <= en; i += 4u) {                 // ds_read_b128 body
                        float4 v4 = *reinterpret_cast<const float4*>(&ssort[i]);
                        float m0 = (v4.x < tf) ? v4.x : 0.0f;
                        float m1 = (v4.y < tf) ? v4.y : 0.0f;
                        float m2 = (v4.z < tf) ? v4.z : 0.0f;
                        float m3 = (v4.w < tf) ? v4.w : 0.0f;
                        cnt += (v4.x < tf); cnt += (v4.y < tf);
                        cnt += (v4.z < tf); cnt += (v4.w < tf);
                        s1 += (double)((m0 + m1) + (m2 + m3));
                    }
                    for (; i < en; i++) {                           // tail
                        float v = ssort[i];
                        if (v < tf) { cnt++; s1 += (double)v; }
                    }
                    Cc = (double)st + (double)cnt;
                    C1 = S1p[bf] + s1;
                } else {
                    Cc = (double)len; C1 = totS1;
                }
                double ms = (double)(j - zi) * sd;
                sc += ms * (ms * (Cc - prevC) - 2.0 * (C1 - prev1));
                prevC = Cc; prev1 = C1;
            }
            atomicAdd(&L.score[cand], sc);            // device-scope fp64
        }
    }

    // ---- Ph H: last-block ticket + wave-reduce argmin ----
    __syncthreads();
    if (tid == 0) {
        __threadfence();
        unsigned old = atomicAdd(&L.ctrs[1], 1u);
        islast = (old == gridDim.x - 1) ? 1 : 0;
    }
    __syncthreads();
    if (!islast) return;
    __threadfence();

    double best = 1.0e300; int bidx = 0x7fffffff;
    for (int c = tid; c < NCAND; c += BLK) {
        double sc = agent_load_f64(&L.score[c]);
        if (sc < best) { best = sc; bidx = c; }       // ascending c keeps first-min
    }
    #pragma unroll
    for (int off = 32; off > 0; off >>= 1) {
        double so = __shfl_xor(best, off); int io = __shfl_xor(bidx, off);
        if (so < best || (so == best && io < bidx)) { best = so; bidx = io; }
    }
    if (lane == 0) { wsd[wv] = best; wsu[wv] = (unsigned)bidx; }
    __syncthreads();
    if (tid == 0) {
        double bs = wsd[0]; int bi = (int)wsu[0];
        for (int k = 1; k < 16; k++) {
            double so = wsd[k]; int io = (int)wsu[k];
            if (so < bs || (so == bs && io < bi)) { bs = so; bi = io; }
        }
        float bmin = x_min, bmax = x_max;
        if (bi != 0x7fffffff) {
#pragma clang fp contract(off)
            float step = rangef / 100.0f;
            int ii = bi >> 4, z = bi & 15;
            float fi = (float)(ii + 1);
            float tmp_max   = step * fi;
            float tmp_delta = tmp_max / 15.0f;
            float t = (float)z * tmp_delta;
            bmin = fmaxf(-t, x_min);
            bmax = fminf(tmp_max - t, x_max);
        }
        out[0] = bmin; out[1] = bmax;
    }
}

// ================= fallback path (round-1 proven) =================
__global__ __launch_bounds__(256) void k_params_fb(const float* __restrict__ x, int n4,
                                                   float4* __restrict__ params,
                                                   float2* __restrict__ ranges,
                                                   double* __restrict__ score,
                                                   float* __restrict__ mm) {
#pragma clang fp contract(off)
    __shared__ float smin[256], smax[256];
    const float4* x4 = (const float4*)x;
    float lmin = 3.0e38f, lmax = -3.0e38f;
    for (int i = threadIdx.x; i < n4; i += 256) {
        float4 v = x4[i];
        lmin = fminf(lmin, fminf(fminf(v.x, v.y), fminf(v.z, v.w)));
        lmax = fmaxf(lmax, fmaxf(fmaxf(v.x, v.y), fmaxf(v.z, v.w)));
    }
    smin[threadIdx.x] = lmin; smax[threadIdx.x] = lmax;
    __syncthreads();
    for (int s = 128; s > 0; s >>= 1) {
        if (threadIdx.x < s) {
            smin[threadIdx.x] = fminf(smin[threadIdx.x], smin[threadIdx.x + s]);
            smax[threadIdx.x] = fmaxf(smax[threadIdx.x], smax[threadIdx.x + s]);
        }
        __syncthreads();
    }
    float x_min = smin[0], x_max = smax[0];
    if (threadIdx.x == 0) { mm[0] = x_min; mm[1] = x_max; }
    float xrange = x_max - x_min;
    float step = xrange / 100.0f;
    for (int c = threadIdx.x; c < NCAND; c += 256) {
        int ii = c >> 4;
        int z  = c & 15;
        float fi = (float)(ii + 1);
        float tmp_max   = step * fi;
        float tmp_delta = tmp_max / 15.0f;
        float t = (float)z * tmp_delta;
        float new_min = fmaxf(-t, x_min);
        float new_max = fminf(tmp_max - t, x_max);
        float min_neg = fminf(new_min, 0.0f);
        float max_pos = fmaxf(new_max, 0.0f);
        float scale = fmaxf((max_pos - min_neg) / 15.0f, F32_EPS);
        float zp = 0.0f - rintf(min_neg / scale);
        zp = fminf(fmaxf(zp, 0.0f), 15.0f);
        float inv = (float)(1.0 / (double)scale);
        params[c] = make_float4(scale, inv, 0.0f - zp, 15.0f - zp);
        ranges[c] = make_float2(new_min, new_max);
        score[c]  = 0.0;
    }
}

__global__ __launch_bounds__(256) void k_score_bf(const float* __restrict__ x, int n4,
                                                  const float4* __restrict__ params,
                                                  double* __restrict__ score) {
    const int tid = blockIdx.x * 256 + threadIdx.x;
    const int T = gridDim.x * 256;
    const float4* x4 = (const float4*)x;
    float xs[16];
    #pragma unroll
    for (int k = 0; k < 4; k++) {
        int i4 = tid + k * T;
        float4 v;
        if (i4 < n4) v = x4[i4];
        else { v.x = 0.0f; v.y = 0.0f; v.z = 0.0f; v.w = 0.0f; }
        xs[4*k+0] = v.x; xs[4*k+1] = v.y; xs[4*k+2] = v.z; xs[4*k+3] = v.w;
    }
    int c = (int)((blockIdx.x * 37u) % NCAND);
    for (int k = 0; k < NCAND; k++) {
        float4 p = params[c];
        float s   = rfl_f(p.x);
        float inv = rfl_f(p.y);
        float lo  = rfl_f(p.z);
        float hi  = rfl_f(p.w);
        float acc = 0.0f;
        #pragma unroll
        for (int e = 0; e < 16; e++) {
            float r = rintf(xs[e] * inv);
            r = fminf(fmaxf(r, lo), hi);
            float d = fmaf(r, s, -xs[e]);
            acc = fmaf(d, d, acc);
        }
        #pragma unroll
        for (int off = 32; off > 0; off >>= 1)
            acc += __shfl_xor(acc, off);
        if ((threadIdx.x & 63) == 0)
            atomicAdd(&score[c], (double)acc);
        c++; if (c >= NCAND) c -= NCAND;
    }
}

__global__ void k_final_fb(const double* __restrict__ score,
                           const float2* __restrict__ ranges,
                           const float* __restrict__ mm,
                           float* __restrict__ out) {
    if (blockIdx.x == 0 && threadIdx.x == 0) {
        double best = 1.0e300;
        float bmin = mm[0], bmax = mm[1];
        for (int c = 0; c < NCAND; c++) {
            double sc = score[c];
            if (sc < best) { best = sc; bmin = ranges[c].x; bmax = ranges[c].y; }
        }
        out[0] = bmin;
        out[1] = bmax;
    }
}

extern "C" void kernel_launch(void* const* d_in, const int* in_sizes, int n_in,
                              void* d_out, int out_size, void* d_ws, size_t ws_size,
                              hipStream_t stream) {
    const float* x = (const float*)d_in[0];
    int n  = in_sizes[0];          // 4194304
    int n4 = n / 4;
    float* out = (float*)d_out;
    WSL L = make_ws((char*)d_ws);

    int per4 = (n4 + G2 - 1) / G2;
    bool ok = (ws_size >= L.small_needed) && ((n % 4) == 0) && (per4 * 4 <= SLICE) && (n4 > 0);

    if (ok) {
        hipMemsetAsync(d_ws, 0, 64, stream);             // ticket/barrier counters only
        k_fused<<<G2, BLK, 0, stream>>>(x, n4, (char*)d_ws, out);
    } else if (ws_size >= L.small_needed) {
        k_params_fb<<<1, 256, 0, stream>>>(x, n4, L.params, L.ranges, L.scoreFB, L.mm);
        int blocks = ((n4 + 3) / 4 + 255) / 256;
        k_score_bf<<<blocks, 256, 0, stream>>>(x, n4, L.params, L.scoreFB);
        k_final_fb<<<1, 64, 0, stream>>>(L.scoreFB, L.ranges, L.mm, out);
    }
}